// Round 7
// baseline (783.597 us; speedup 1.0000x reference)
//
#include <hip/hip_runtime.h>
#include <math.h>

#define HID 64
#define BN_EPS 1e-5f
#define NBMAX 256

typedef unsigned int uint;
typedef unsigned short ushort;

// ============ radix-bucketed CSR build ============

__global__ __launch_bounds__(256) void k_bucket_hist(const int* __restrict__ ei, int E, int NB,
                                                     int* __restrict__ bcnt_d, int* __restrict__ bcnt_s) {
    __shared__ int hd[NBMAX], hs[NBMAX];
    int t = threadIdx.x;
    if (t < NB) { hd[t] = 0; hs[t] = 0; }
    __syncthreads();
    for (int e = blockIdx.x * 256 + t; e < E; e += gridDim.x * 256) {
        int src = ei[e], dst = ei[E + e];
        atomicAdd(&hs[src >> 8], 1);
        atomicAdd(&hd[dst >> 8], 1);
    }
    __syncthreads();
    if (t < NB) {
        if (hd[t]) atomicAdd(&bcnt_d[t], hd[t]);
        if (hs[t]) atomicAdd(&bcnt_s[t], hs[t]);
    }
}

__global__ __launch_bounds__(256) void k_bucket_scan(const int* __restrict__ bcnt_d, const int* __restrict__ bcnt_s,
                                                     int NB, int N, int E,
                                                     int* __restrict__ bbase_d, int* __restrict__ cursor_d,
                                                     int* __restrict__ bbase_s, int* __restrict__ cursor_s,
                                                     int* __restrict__ rowptr) {
    __shared__ int sh[256];
    int t = threadIdx.x;
    int v = (t < NB) ? bcnt_d[t] : 0;
    sh[t] = v; __syncthreads();
    for (int s = 1; s < 256; s <<= 1) { int u = (t >= s) ? sh[t - s] : 0; __syncthreads(); sh[t] += u; __syncthreads(); }
    int excl = sh[t] - v;
    if (t <= NB) bbase_d[t] = excl;
    if (t < NB) cursor_d[t] = excl;
    if (t == 0) rowptr[N] = E;
    __syncthreads();
    v = (t < NB) ? bcnt_s[t] : 0;
    sh[t] = v; __syncthreads();
    for (int s = 1; s < 256; s <<= 1) { int u = (t >= s) ? sh[t - s] : 0; __syncthreads(); sh[t] += u; __syncthreads(); }
    excl = sh[t] - v;
    if (t <= NB) bbase_s[t] = excl;
    if (t < NB) cursor_s[t] = excl;
}

__global__ __launch_bounds__(256) void k_scatter(const int* __restrict__ ei, int E, int NB,
                                                 int* __restrict__ cursor_d, int* __restrict__ cursor_s,
                                                 unsigned long long* __restrict__ bedge, int* __restrict__ bsrc) {
    __shared__ int hd[NBMAX], hs[NBMAX], curd[NBMAX], curs[NBMAX];
    int t = threadIdx.x;
    int chunk = (E + gridDim.x - 1) / gridDim.x;
    int e0 = blockIdx.x * chunk;
    int e1 = min(e0 + chunk, E);
    if (t < NB) { hd[t] = 0; hs[t] = 0; }
    __syncthreads();
    for (int e = e0 + t; e < e1; e += 256) {
        int src = ei[e], dst = ei[E + e];
        atomicAdd(&hd[dst >> 8], 1);
        atomicAdd(&hs[src >> 8], 1);
    }
    __syncthreads();
    if (t < NB) {
        curd[t] = hd[t] ? atomicAdd(&cursor_d[t], hd[t]) : 0;
        curs[t] = hs[t] ? atomicAdd(&cursor_s[t], hs[t]) : 0;
    }
    __syncthreads();
    for (int e = e0 + t; e < e1; e += 256) {
        int src = ei[e], dst = ei[E + e];
        int pd = atomicAdd(&curd[dst >> 8], 1);
        bedge[pd] = ((unsigned long long)(uint)dst << 32) | (uint)src;
        int ps = atomicAdd(&curs[src >> 8], 1);
        bsrc[ps] = src;
    }
}

__global__ __launch_bounds__(256) void k_build_csr(const unsigned long long* __restrict__ bedge,
                                                   const int* __restrict__ bbase_d, int N,
                                                   int* __restrict__ rowptr, int* __restrict__ eidx) {
    __shared__ int h[256], off[256], cur[256];
    int t = threadIdx.x, b = blockIdx.x;
    int base = bbase_d[b], end = bbase_d[b + 1];
    h[t] = 0; __syncthreads();
    for (int p = base + t; p < end; p += 256)
        atomicAdd(&h[(int)(bedge[p] >> 32) & 255], 1);
    __syncthreads();
    off[t] = h[t]; __syncthreads();
    for (int s = 1; s < 256; s <<= 1) { int u = (t >= s) ? off[t - s] : 0; __syncthreads(); off[t] += u; __syncthreads(); }
    int excl = off[t] - h[t];
    int node = (b << 8) + t;
    if (node <= N) rowptr[node] = base + excl;
    cur[t] = excl; __syncthreads();
    for (int p = base + t; p < end; p += 256) {
        unsigned long long be = bedge[p];
        int bin = (int)(be >> 32) & 255;
        int pos = atomicAdd(&cur[bin], 1);
        eidx[base + pos] = (int)(uint)(be & 0xffffffffULL);
    }
}

__global__ __launch_bounds__(256) void k_outdeg(const int* __restrict__ bsrc, const int* __restrict__ bbase_s,
                                                int N, float* __restrict__ dis) {
    __shared__ int h[256];
    int t = threadIdx.x, b = blockIdx.x;
    int base = bbase_s[b], end = bbase_s[b + 1];
    h[t] = 0; __syncthreads();
    for (int p = base + t; p < end; p += 256) atomicAdd(&h[bsrc[p] & 255], 1);
    __syncthreads();
    int node = (b << 8) + t;
    if (node < N) dis[node] = rsqrtf((float)(h[t] + 1));
}

// ============ BN stats: float4 loads, two-stage deterministic reduction ============
// Stage 1: per-block float4 partial sums/sumsq -> partial[b][0:F)=s, partial[b][F:2F)=q.
// Stage 2: k_stats_final sums partials over blocks -> stats[f], stats[F+f].

template <int F>
__global__ __launch_bounds__(256) void k_stats(const float* __restrict__ X, int n,
                                               float* __restrict__ partial) {
    constexpr int C4 = F / 4;           // float4 groups per row: 32 (F=128) / 16 (F=64)
    constexpr int RPB = 256 / C4;       // row-subs per block: 8 / 16
    int t = threadIdx.x;
    int c4 = t % C4;
    int rsub = t / C4;
    float4 s = make_float4(0.f, 0.f, 0.f, 0.f);
    float4 q = make_float4(0.f, 0.f, 0.f, 0.f);
    for (int r = blockIdx.x * RPB + rsub; r < n; r += gridDim.x * RPB) {
        float4 v = *(const float4*)(X + (size_t)r * F + 4 * c4);   // coalesced 16B/lane
        s.x += v.x; s.y += v.y; s.z += v.z; s.w += v.w;
        q.x = fmaf(v.x, v.x, q.x); q.y = fmaf(v.y, v.y, q.y);
        q.z = fmaf(v.z, v.z, q.z); q.w = fmaf(v.w, v.w, q.w);
    }
    __shared__ float4 shs[256], shq[256];
    shs[t] = s; shq[t] = q;
    __syncthreads();
    if (rsub == 0) {   // first C4 threads reduce over row-subs
        #pragma unroll
        for (int k = 1; k < RPB; k++) {
            float4 a = shs[t + k * C4], b = shq[t + k * C4];
            s.x += a.x; s.y += a.y; s.z += a.z; s.w += a.w;
            q.x += b.x; q.y += b.y; q.z += b.z; q.w += b.w;
        }
        float* p = partial + (size_t)blockIdx.x * (2 * F);
        *(float4*)(p + 4 * c4) = s;
        *(float4*)(p + F + 4 * c4) = q;
    }
}

// one block, 2F threads; stats[j] = sum_b partial[b][j]
template <int F>
__global__ void k_stats_final(const float* __restrict__ partial, int nblocks,
                              float* __restrict__ stats) {
    int j = threadIdx.x;   // 0..2F-1
    float acc = 0.f;
    for (int b = 0; b < nblocks; ++b) acc += partial[(size_t)b * (2 * F) + j];
    stats[j] = acc;
}

// ============ fold BN into linear ============
// stats layout: [0:K) = sum, [K:2K) = sumsq

template <int K>
__global__ void k_fold(const float* __restrict__ stats, const float* __restrict__ gamma,
                       const float* __restrict__ beta, const float* __restrict__ W,
                       const float* __restrict__ bias, float n_inv,
                       float* __restrict__ Wout, float* __restrict__ bout, int has_bias) {
    int o = blockIdx.x;
    int f = threadIdx.x;
    float mu = stats[f] * n_inv;
    float var = stats[K + f] * n_inv - mu * mu;
    float a = gamma[f] * rsqrtf(var + BN_EPS);
    float w = W[(size_t)f * HID + o];
    Wout[(size_t)f * HID + o] = a * w;
    float contrib = (beta[f] - mu * a) * w;
    __shared__ float sh[K];
    sh[f] = contrib;
    __syncthreads();
    #pragma unroll
    for (int off = K / 2; off > 0; off >>= 1) {
        if (f < off) sh[f] += sh[f + off];
        __syncthreads();
    }
    if (f == 0) bout[o] = sh[0] + (has_bias ? bias[o] : 0.f);
}

// ============ GEMM: classic 2D tile, 4x4 register tile per thread ============

__device__ inline uint bf16pk(float a, float b) {
    uint ua = __builtin_bit_cast(uint, a);
    ua += 0x7fff + ((ua >> 16) & 1);
    uint ub = __builtin_bit_cast(uint, b);
    ub += 0x7fff + ((ub >> 16) & 1);
    return (ua >> 16) | (ub & 0xffff0000u);
}

template <int K, bool RELU, bool DIS>
__global__ __launch_bounds__(256) void k_gemm(const float* __restrict__ X, const float* __restrict__ W,
                                              const float* __restrict__ bias, const float* __restrict__ dis,
                                              void* __restrict__ out, int n) {
    constexpr int MT = 64;
    constexpr int KC = 64;
    constexpr int XS = 68;
    __shared__ float Xs[KC * XS];
    __shared__ float Ws[KC * HID];

    int t = threadIdx.x;
    int tx = t & 15;
    int ty = t >> 4;
    int row0 = blockIdx.x * MT;

    float acc[4][4];
    #pragma unroll
    for (int i = 0; i < 4; i++)
        #pragma unroll
        for (int j = 0; j < 4; j++) acc[i][j] = 0.f;

    for (int kc = 0; kc < K; kc += KC) {
        #pragma unroll
        for (int it = 0; it < 4; ++it) {
            int id = t + 256 * it;
            int r = id >> 4;
            int c4 = id & 15;
            float4 v = make_float4(0.f, 0.f, 0.f, 0.f);
            if (row0 + r < n) v = *(const float4*)(X + (size_t)(row0 + r) * K + kc + 4 * c4);
            int kk = 4 * c4;
            Xs[(kk + 0) * XS + r] = v.x;
            Xs[(kk + 1) * XS + r] = v.y;
            Xs[(kk + 2) * XS + r] = v.z;
            Xs[(kk + 3) * XS + r] = v.w;
        }
        {
            const float4* wsrc = (const float4*)(W + (size_t)kc * HID);
            #pragma unroll
            for (int it = 0; it < 4; ++it) {
                int id = t + 256 * it;
                ((float4*)Ws)[id] = wsrc[id];
            }
        }
        __syncthreads();

        #pragma unroll 8
        for (int k = 0; k < KC; ++k) {
            float4 xv = *(const float4*)&Xs[k * XS + 4 * ty];
            float4 wv = *(const float4*)&Ws[k * HID + 4 * tx];
            acc[0][0] = fmaf(xv.x, wv.x, acc[0][0]);
            acc[0][1] = fmaf(xv.x, wv.y, acc[0][1]);
            acc[0][2] = fmaf(xv.x, wv.z, acc[0][2]);
            acc[0][3] = fmaf(xv.x, wv.w, acc[0][3]);
            acc[1][0] = fmaf(xv.y, wv.x, acc[1][0]);
            acc[1][1] = fmaf(xv.y, wv.y, acc[1][1]);
            acc[1][2] = fmaf(xv.y, wv.z, acc[1][2]);
            acc[1][3] = fmaf(xv.y, wv.w, acc[1][3]);
            acc[2][0] = fmaf(xv.z, wv.x, acc[2][0]);
            acc[2][1] = fmaf(xv.z, wv.y, acc[2][1]);
            acc[2][2] = fmaf(xv.z, wv.z, acc[2][2]);
            acc[2][3] = fmaf(xv.z, wv.w, acc[2][3]);
            acc[3][0] = fmaf(xv.w, wv.x, acc[3][0]);
            acc[3][1] = fmaf(xv.w, wv.y, acc[3][1]);
            acc[3][2] = fmaf(xv.w, wv.z, acc[3][2]);
            acc[3][3] = fmaf(xv.w, wv.w, acc[3][3]);
        }
        __syncthreads();
    }

    float4 bv = *(const float4*)(bias + 4 * tx);
    #pragma unroll
    for (int i = 0; i < 4; ++i) {
        int row = row0 + 4 * ty + i;
        if (row >= n) break;
        float vx = acc[i][0] + bv.x, vy = acc[i][1] + bv.y;
        float vz = acc[i][2] + bv.z, vw = acc[i][3] + bv.w;
        if constexpr (DIS) {
            float d = dis[row];
            uint2 pk;
            pk.x = bf16pk(vx * d, vy * d);
            pk.y = bf16pk(vz * d, vw * d);
            *(uint2*)((ushort*)out + (size_t)row * HID + 4 * tx) = pk;
        } else {
            float4 v;
            v.x = RELU ? fmaxf(vx, 0.f) : vx;
            v.y = RELU ? fmaxf(vy, 0.f) : vy;
            v.z = RELU ? fmaxf(vz, 0.f) : vz;
            v.w = RELU ? fmaxf(vw, 0.f) : vw;
            *(float4*)((float*)out + (size_t)row * HID + 4 * tx) = v;
        }
    }
}

// ============ aggregation ============

__device__ inline float bfl(uint v) { return __builtin_bit_cast(float, v << 16); }
__device__ inline float bfh(uint v) { return __builtin_bit_cast(float, v & 0xffff0000u); }

__global__ __launch_bounds__(256) void k_agg(const ushort* __restrict__ s, const int* __restrict__ rowptr,
                                             const int* __restrict__ eidx, const float* __restrict__ dis,
                                             const float* __restrict__ bias, float* __restrict__ out, int n) {
    int wave = threadIdx.x >> 6;
    int lane = threadIdx.x & 63;
    int half = lane >> 5, li = lane & 31;
    int i = blockIdx.x * 8 + wave * 2 + half;
    if (i >= n) return;
    int f = li * 2;
    const uint* sp = (const uint*)s;
    uint v = sp[(size_t)i * 32 + li];
    float ax = bfl(v), ay = bfh(v);
    int q = rowptr[i], qe = rowptr[i + 1];
    for (; q + 4 <= qe; q += 4) {
        int j0 = eidx[q], j1 = eidx[q + 1], j2 = eidx[q + 2], j3 = eidx[q + 3];
        uint v0 = sp[(size_t)j0 * 32 + li];
        uint v1 = sp[(size_t)j1 * 32 + li];
        uint v2 = sp[(size_t)j2 * 32 + li];
        uint v3 = sp[(size_t)j3 * 32 + li];
        ax += (bfl(v0) + bfl(v1)) + (bfl(v2) + bfl(v3));
        ay += (bfh(v0) + bfh(v1)) + (bfh(v2) + bfh(v3));
    }
    for (; q < qe; ++q) {
        uint vv = sp[(size_t)eidx[q] * 32 + li];
        ax += bfl(vv); ay += bfh(vv);
    }
    float dd = dis[i];
    float2 r;
    r.x = fmaxf(fmaf(dd, ax, bias[f]), 0.f);
    r.y = fmaxf(fmaf(dd, ay, bias[f + 1]), 0.f);
    *(float2*)(out + (size_t)i * HID + f) = r;
}

// ============ global_add_pool ============

__global__ __launch_bounds__(256) void k_pool(const float* __restrict__ h, const int* __restrict__ batch,
                                              int n, float* __restrict__ out) {
    int g = blockIdx.x;
    int lo = 0, hi = n;
    while (lo < hi) { int mid = (lo + hi) >> 1; if (batch[mid] < g) lo = mid + 1; else hi = mid; }
    int start = lo;
    hi = n;
    while (lo < hi) { int mid = (lo + hi) >> 1; if (batch[mid] < g + 1) lo = mid + 1; else hi = mid; }
    int end = lo;
    int lane = threadIdx.x & 63;
    int rs = threadIdx.x >> 6;
    float acc = 0.f;
    for (int r = start + rs; r < end; r += 4) acc += h[(size_t)r * HID + lane];
    __shared__ float sh[256];
    sh[threadIdx.x] = acc;
    __syncthreads();
    if (threadIdx.x < 64) {
        acc = sh[threadIdx.x] + sh[64 + threadIdx.x] + sh[128 + threadIdx.x] + sh[192 + threadIdx.x];
        out[(size_t)g * HID + threadIdx.x] = acc;
    }
}

// ============ driver ============

extern "C" void kernel_launch(void* const* d_in, const int* in_sizes, int n_in,
                              void* d_out, int out_size, void* d_ws, size_t ws_size,
                              hipStream_t stream) {
    const float* x     = (const float*)d_in[0];
    const int*   ei    = (const int*)d_in[1];
    const int*   batch = (const int*)d_in[2];
    const float* bnfg  = (const float*)d_in[3];
    const float* bnfb  = (const float*)d_in[4];
    const float* Wfeat = (const float*)d_in[5];
    const float* bfeat = (const float*)d_in[6];
    const float* bng   = (const float*)d_in[7];
    const float* bnb   = (const float*)d_in[8];
    const float* Ws    = (const float*)d_in[9];
    const float* bs    = (const float*)d_in[10];
    float* out = (float*)d_out;

    const int N   = in_sizes[2];
    const int E   = in_sizes[1] / 2;
    const int FIN = in_sizes[0] / N;
    const int L   = in_sizes[9] / (HID * HID);
    const int G   = out_size / HID;
    const int NB  = (N + 255) >> 8;
    const int SB  = 512;                 // stats stage-1 blocks

    char* w = (char*)d_ws;
    auto alloc = [&](size_t bytes) { char* p = w; w += (bytes + 255) & ~(size_t)255; return p; };
    int*   bcnt_d = (int*)alloc(256 * 4);
    int*   bcnt_s = (int*)alloc(256 * 4);
    size_t zero_bytes = (size_t)(w - (char*)d_ws);
    float* stats    = (float*)alloc(1024 * 4);
    float* spartial = (float*)alloc((size_t)SB * 256 * 4);   // 512 KB
    int*   bbase_d  = (int*)alloc(257 * 4);
    int*   cursor_d = (int*)alloc(256 * 4);
    int*   bbase_s  = (int*)alloc(257 * 4);
    int*   cursor_s = (int*)alloc(256 * 4);
    int*   rowptr   = (int*)alloc(((size_t)N + 1) * 4);
    int*   eidx     = (int*)alloc((size_t)E * 4);
    float* dis      = (float*)alloc((size_t)N * 4);
    float* Wf       = (float*)alloc((size_t)FIN * HID * 4);
    float* bf       = (float*)alloc(HID * 4);
    float* bufA     = (float*)alloc((size_t)N * HID * 4);
    ushort* bufB    = (ushort*)alloc((size_t)N * HID * 2);
    unsigned long long* bedge = (unsigned long long*)bufA;
    int* bsrc = (int*)bufB;

    hipMemsetAsync(d_ws, 0, zero_bytes, stream);

    int gG = (N + 63) / 64;

    // graph build
    k_bucket_hist<<<256, 256, 0, stream>>>(ei, E, NB, bcnt_d, bcnt_s);
    k_bucket_scan<<<1, 256, 0, stream>>>(bcnt_d, bcnt_s, NB, N, E,
                                         bbase_d, cursor_d, bbase_s, cursor_s, rowptr);
    k_scatter<<<256, 256, 0, stream>>>(ei, E, NB, cursor_d, cursor_s, bedge, bsrc);
    k_build_csr<<<NB, 256, 0, stream>>>(bedge, bbase_d, N, rowptr, eidx);
    k_outdeg<<<NB, 256, 0, stream>>>(bsrc, bbase_s, N, dis);

    // feature layer
    k_stats<128><<<SB, 256, 0, stream>>>(x, N, spartial);
    k_stats_final<128><<<1, 256, 0, stream>>>(spartial, SB, stats);
    k_fold<128><<<HID, 128, 0, stream>>>(stats, bnfg, bnfb, Wfeat, bfeat, 1.f / (float)N, Wf, bf, 1);
    k_gemm<128, true, false><<<gG, 256, 0, stream>>>(x, Wf, bf, dis, bufA, N);

    // GCN layers
    for (int l = 0; l < L; ++l) {
        k_stats<64><<<SB, 256, 0, stream>>>(bufA, N, spartial);
        k_stats_final<64><<<1, 128, 0, stream>>>(spartial, SB, stats);
        k_fold<64><<<HID, 64, 0, stream>>>(stats, bng + (size_t)l * HID, bnb + (size_t)l * HID,
                                           Ws + (size_t)l * HID * HID, bf /*unused*/,
                                           1.f / (float)N, Wf, bf, 0);
        k_gemm<64, false, true><<<gG, 256, 0, stream>>>(bufA, Wf, bf, dis, (void*)bufB, N);
        k_agg<<<(N + 7) / 8, 256, 0, stream>>>(bufB, rowptr, eidx, dis, bs + (size_t)l * HID, bufA, N);
    }

    k_pool<<<G, 256, 0, stream>>>(bufA, batch, N, out);
}

// Round 8
// 320.122 us; speedup vs baseline: 2.4478x; 2.4478x over previous
//
#include <hip/hip_runtime.h>
#include <math.h>

#define HID 64
#define BN_EPS 1e-5f
#define NBMAX 256

typedef unsigned int uint;
typedef unsigned short ushort;

// ============ radix-bucketed CSR build ============

__global__ __launch_bounds__(256) void k_bucket_hist(const int* __restrict__ ei, int E, int NB,
                                                     int* __restrict__ bcnt_d, int* __restrict__ bcnt_s) {
    __shared__ int hd[NBMAX], hs[NBMAX];
    int t = threadIdx.x;
    if (t < NB) { hd[t] = 0; hs[t] = 0; }
    __syncthreads();
    for (int e = blockIdx.x * 256 + t; e < E; e += gridDim.x * 256) {
        int src = ei[e], dst = ei[E + e];
        atomicAdd(&hs[src >> 8], 1);
        atomicAdd(&hd[dst >> 8], 1);
    }
    __syncthreads();
    if (t < NB) {
        if (hd[t]) atomicAdd(&bcnt_d[t], hd[t]);
        if (hs[t]) atomicAdd(&bcnt_s[t], hs[t]);
    }
}

__global__ __launch_bounds__(256) void k_bucket_scan(const int* __restrict__ bcnt_d, const int* __restrict__ bcnt_s,
                                                     int NB, int N, int E,
                                                     int* __restrict__ bbase_d, int* __restrict__ cursor_d,
                                                     int* __restrict__ bbase_s, int* __restrict__ cursor_s,
                                                     int* __restrict__ rowptr) {
    __shared__ int sh[256];
    int t = threadIdx.x;
    int v = (t < NB) ? bcnt_d[t] : 0;
    sh[t] = v; __syncthreads();
    for (int s = 1; s < 256; s <<= 1) { int u = (t >= s) ? sh[t - s] : 0; __syncthreads(); sh[t] += u; __syncthreads(); }
    int excl = sh[t] - v;
    if (t <= NB) bbase_d[t] = excl;
    if (t < NB) cursor_d[t] = excl;
    if (t == 0) rowptr[N] = E;
    __syncthreads();
    v = (t < NB) ? bcnt_s[t] : 0;
    sh[t] = v; __syncthreads();
    for (int s = 1; s < 256; s <<= 1) { int u = (t >= s) ? sh[t - s] : 0; __syncthreads(); sh[t] += u; __syncthreads(); }
    excl = sh[t] - v;
    if (t <= NB) bbase_s[t] = excl;
    if (t < NB) cursor_s[t] = excl;
}

__global__ __launch_bounds__(256) void k_scatter(const int* __restrict__ ei, int E, int NB,
                                                 int* __restrict__ cursor_d, int* __restrict__ cursor_s,
                                                 unsigned long long* __restrict__ bedge, int* __restrict__ bsrc) {
    __shared__ int hd[NBMAX], hs[NBMAX], curd[NBMAX], curs[NBMAX];
    int t = threadIdx.x;
    int chunk = (E + gridDim.x - 1) / gridDim.x;
    int e0 = blockIdx.x * chunk;
    int e1 = min(e0 + chunk, E);
    if (t < NB) { hd[t] = 0; hs[t] = 0; }
    __syncthreads();
    for (int e = e0 + t; e < e1; e += 256) {
        int src = ei[e], dst = ei[E + e];
        atomicAdd(&hd[dst >> 8], 1);
        atomicAdd(&hs[src >> 8], 1);
    }
    __syncthreads();
    if (t < NB) {
        curd[t] = hd[t] ? atomicAdd(&cursor_d[t], hd[t]) : 0;
        curs[t] = hs[t] ? atomicAdd(&cursor_s[t], hs[t]) : 0;
    }
    __syncthreads();
    for (int e = e0 + t; e < e1; e += 256) {
        int src = ei[e], dst = ei[E + e];
        int pd = atomicAdd(&curd[dst >> 8], 1);
        bedge[pd] = ((unsigned long long)(uint)dst << 32) | (uint)src;
        int ps = atomicAdd(&curs[src >> 8], 1);
        bsrc[ps] = src;
    }
}

__global__ __launch_bounds__(256) void k_build_csr(const unsigned long long* __restrict__ bedge,
                                                   const int* __restrict__ bbase_d, int N,
                                                   int* __restrict__ rowptr, int* __restrict__ eidx) {
    __shared__ int h[256], off[256], cur[256];
    int t = threadIdx.x, b = blockIdx.x;
    int base = bbase_d[b], end = bbase_d[b + 1];
    h[t] = 0; __syncthreads();
    for (int p = base + t; p < end; p += 256)
        atomicAdd(&h[(int)(bedge[p] >> 32) & 255], 1);
    __syncthreads();
    off[t] = h[t]; __syncthreads();
    for (int s = 1; s < 256; s <<= 1) { int u = (t >= s) ? off[t - s] : 0; __syncthreads(); off[t] += u; __syncthreads(); }
    int excl = off[t] - h[t];
    int node = (b << 8) + t;
    if (node <= N) rowptr[node] = base + excl;
    cur[t] = excl; __syncthreads();
    for (int p = base + t; p < end; p += 256) {
        unsigned long long be = bedge[p];
        int bin = (int)(be >> 32) & 255;
        int pos = atomicAdd(&cur[bin], 1);
        eidx[base + pos] = (int)(uint)(be & 0xffffffffULL);
    }
}

__global__ __launch_bounds__(256) void k_outdeg(const int* __restrict__ bsrc, const int* __restrict__ bbase_s,
                                                int N, float* __restrict__ dis) {
    __shared__ int h[256];
    int t = threadIdx.x, b = blockIdx.x;
    int base = bbase_s[b], end = bbase_s[b + 1];
    h[t] = 0; __syncthreads();
    for (int p = base + t; p < end; p += 256) atomicAdd(&h[bsrc[p] & 255], 1);
    __syncthreads();
    int node = (b << 8) + t;
    if (node < N) dis[node] = rsqrtf((float)(h[t] + 1));
}

// ============ BN stats: float4 loads, two-stage deterministic reduction ============

template <int F>
__global__ __launch_bounds__(256) void k_stats(const float* __restrict__ X, int n,
                                               float* __restrict__ partial) {
    constexpr int C4 = F / 4;
    constexpr int RPB = 256 / C4;
    int t = threadIdx.x;
    int c4 = t % C4;
    int rsub = t / C4;
    float4 s = make_float4(0.f, 0.f, 0.f, 0.f);
    float4 q = make_float4(0.f, 0.f, 0.f, 0.f);
    for (int r = blockIdx.x * RPB + rsub; r < n; r += gridDim.x * RPB) {
        float4 v = *(const float4*)(X + (size_t)r * F + 4 * c4);
        s.x += v.x; s.y += v.y; s.z += v.z; s.w += v.w;
        q.x = fmaf(v.x, v.x, q.x); q.y = fmaf(v.y, v.y, q.y);
        q.z = fmaf(v.z, v.z, q.z); q.w = fmaf(v.w, v.w, q.w);
    }
    __shared__ float4 shs[256], shq[256];
    shs[t] = s; shq[t] = q;
    __syncthreads();
    if (rsub == 0) {
        #pragma unroll
        for (int k = 1; k < RPB; k++) {
            float4 a = shs[t + k * C4], b = shq[t + k * C4];
            s.x += a.x; s.y += a.y; s.z += a.z; s.w += a.w;
            q.x += b.x; q.y += b.y; q.z += b.z; q.w += b.w;
        }
        float* p = partial + (size_t)blockIdx.x * (2 * F);
        *(float4*)(p + 4 * c4) = s;
        *(float4*)(p + F + 4 * c4) = q;
    }
}

// grid = 2F blocks, 256 threads: block j reduces partial[:, j] over nblocks entries.
template <int F>
__global__ __launch_bounds__(256) void k_stats_final(const float* __restrict__ partial, int nblocks,
                                                     float* __restrict__ stats) {
    int j = blockIdx.x;          // 0..2F-1
    int t = threadIdx.x;
    float acc = 0.f;
    for (int b = t; b < nblocks; b += 256) acc += partial[(size_t)b * (2 * F) + j];
    __shared__ float sh[256];
    sh[t] = acc;
    __syncthreads();
    #pragma unroll
    for (int off = 128; off > 0; off >>= 1) {
        if (t < off) sh[t] += sh[t + off];
        __syncthreads();
    }
    if (t == 0) stats[j] = sh[0];
}

// ============ fold BN into linear ============
// stats layout: [0:K) = sum, [K:2K) = sumsq

template <int K>
__global__ void k_fold(const float* __restrict__ stats, const float* __restrict__ gamma,
                       const float* __restrict__ beta, const float* __restrict__ W,
                       const float* __restrict__ bias, float n_inv,
                       float* __restrict__ Wout, float* __restrict__ bout, int has_bias) {
    int o = blockIdx.x;
    int f = threadIdx.x;
    float mu = stats[f] * n_inv;
    float var = stats[K + f] * n_inv - mu * mu;
    float a = gamma[f] * rsqrtf(var + BN_EPS);
    float w = W[(size_t)f * HID + o];
    Wout[(size_t)f * HID + o] = a * w;
    float contrib = (beta[f] - mu * a) * w;
    __shared__ float sh[K];
    sh[f] = contrib;
    __syncthreads();
    #pragma unroll
    for (int off = K / 2; off > 0; off >>= 1) {
        if (f < off) sh[f] += sh[f + off];
        __syncthreads();
    }
    if (f == 0) bout[o] = sh[0] + (has_bias ? bias[o] : 0.f);
}

// ============ GEMM: classic 2D tile, 4x4 register tile per thread ============

__device__ inline uint bf16pk(float a, float b) {
    uint ua = __builtin_bit_cast(uint, a);
    ua += 0x7fff + ((ua >> 16) & 1);
    uint ub = __builtin_bit_cast(uint, b);
    ub += 0x7fff + ((ub >> 16) & 1);
    return (ua >> 16) | (ub & 0xffff0000u);
}

template <int K, bool RELU, bool DIS>
__global__ __launch_bounds__(256) void k_gemm(const float* __restrict__ X, const float* __restrict__ W,
                                              const float* __restrict__ bias, const float* __restrict__ dis,
                                              void* __restrict__ out, int n) {
    constexpr int MT = 64;
    constexpr int KC = 64;
    constexpr int XS = 68;
    __shared__ float Xs[KC * XS];
    __shared__ float Ws[KC * HID];

    int t = threadIdx.x;
    int tx = t & 15;
    int ty = t >> 4;
    int row0 = blockIdx.x * MT;

    float acc[4][4];
    #pragma unroll
    for (int i = 0; i < 4; i++)
        #pragma unroll
        for (int j = 0; j < 4; j++) acc[i][j] = 0.f;

    for (int kc = 0; kc < K; kc += KC) {
        #pragma unroll
        for (int it = 0; it < 4; ++it) {
            int id = t + 256 * it;
            int r = id >> 4;
            int c4 = id & 15;
            float4 v = make_float4(0.f, 0.f, 0.f, 0.f);
            if (row0 + r < n) v = *(const float4*)(X + (size_t)(row0 + r) * K + kc + 4 * c4);
            int kk = 4 * c4;
            Xs[(kk + 0) * XS + r] = v.x;
            Xs[(kk + 1) * XS + r] = v.y;
            Xs[(kk + 2) * XS + r] = v.z;
            Xs[(kk + 3) * XS + r] = v.w;
        }
        {
            const float4* wsrc = (const float4*)(W + (size_t)kc * HID);
            #pragma unroll
            for (int it = 0; it < 4; ++it) {
                int id = t + 256 * it;
                ((float4*)Ws)[id] = wsrc[id];
            }
        }
        __syncthreads();

        #pragma unroll 8
        for (int k = 0; k < KC; ++k) {
            float4 xv = *(const float4*)&Xs[k * XS + 4 * ty];
            float4 wv = *(const float4*)&Ws[k * HID + 4 * tx];
            acc[0][0] = fmaf(xv.x, wv.x, acc[0][0]);
            acc[0][1] = fmaf(xv.x, wv.y, acc[0][1]);
            acc[0][2] = fmaf(xv.x, wv.z, acc[0][2]);
            acc[0][3] = fmaf(xv.x, wv.w, acc[0][3]);
            acc[1][0] = fmaf(xv.y, wv.x, acc[1][0]);
            acc[1][1] = fmaf(xv.y, wv.y, acc[1][1]);
            acc[1][2] = fmaf(xv.y, wv.z, acc[1][2]);
            acc[1][3] = fmaf(xv.y, wv.w, acc[1][3]);
            acc[2][0] = fmaf(xv.z, wv.x, acc[2][0]);
            acc[2][1] = fmaf(xv.z, wv.y, acc[2][1]);
            acc[2][2] = fmaf(xv.z, wv.z, acc[2][2]);
            acc[2][3] = fmaf(xv.z, wv.w, acc[2][3]);
            acc[3][0] = fmaf(xv.w, wv.x, acc[3][0]);
            acc[3][1] = fmaf(xv.w, wv.y, acc[3][1]);
            acc[3][2] = fmaf(xv.w, wv.z, acc[3][2]);
            acc[3][3] = fmaf(xv.w, wv.w, acc[3][3]);
        }
        __syncthreads();
    }

    float4 bv = *(const float4*)(bias + 4 * tx);
    #pragma unroll
    for (int i = 0; i < 4; ++i) {
        int row = row0 + 4 * ty + i;
        if (row >= n) break;
        float vx = acc[i][0] + bv.x, vy = acc[i][1] + bv.y;
        float vz = acc[i][2] + bv.z, vw = acc[i][3] + bv.w;
        if constexpr (DIS) {
            float d = dis[row];
            uint2 pk;
            pk.x = bf16pk(vx * d, vy * d);
            pk.y = bf16pk(vz * d, vw * d);
            *(uint2*)((ushort*)out + (size_t)row * HID + 4 * tx) = pk;
        } else {
            float4 v;
            v.x = RELU ? fmaxf(vx, 0.f) : vx;
            v.y = RELU ? fmaxf(vy, 0.f) : vy;
            v.z = RELU ? fmaxf(vz, 0.f) : vz;
            v.w = RELU ? fmaxf(vw, 0.f) : vw;
            *(float4*)((float*)out + (size_t)row * HID + 4 * tx) = v;
        }
    }
}

// ============ aggregation ============

__device__ inline float bfl(uint v) { return __builtin_bit_cast(float, v << 16); }
__device__ inline float bfh(uint v) { return __builtin_bit_cast(float, v & 0xffff0000u); }

__global__ __launch_bounds__(256) void k_agg(const ushort* __restrict__ s, const int* __restrict__ rowptr,
                                             const int* __restrict__ eidx, const float* __restrict__ dis,
                                             const float* __restrict__ bias, float* __restrict__ out, int n) {
    int wave = threadIdx.x >> 6;
    int lane = threadIdx.x & 63;
    int half = lane >> 5, li = lane & 31;
    int i = blockIdx.x * 8 + wave * 2 + half;
    if (i >= n) return;
    int f = li * 2;
    const uint* sp = (const uint*)s;
    uint v = sp[(size_t)i * 32 + li];
    float ax = bfl(v), ay = bfh(v);
    int q = rowptr[i], qe = rowptr[i + 1];
    for (; q + 4 <= qe; q += 4) {
        int j0 = eidx[q], j1 = eidx[q + 1], j2 = eidx[q + 2], j3 = eidx[q + 3];
        uint v0 = sp[(size_t)j0 * 32 + li];
        uint v1 = sp[(size_t)j1 * 32 + li];
        uint v2 = sp[(size_t)j2 * 32 + li];
        uint v3 = sp[(size_t)j3 * 32 + li];
        ax += (bfl(v0) + bfl(v1)) + (bfl(v2) + bfl(v3));
        ay += (bfh(v0) + bfh(v1)) + (bfh(v2) + bfh(v3));
    }
    for (; q < qe; ++q) {
        uint vv = sp[(size_t)eidx[q] * 32 + li];
        ax += bfl(vv); ay += bfh(vv);
    }
    float dd = dis[i];
    float2 r;
    r.x = fmaxf(fmaf(dd, ax, bias[f]), 0.f);
    r.y = fmaxf(fmaf(dd, ay, bias[f + 1]), 0.f);
    *(float2*)(out + (size_t)i * HID + f) = r;
}

// ============ global_add_pool ============

__global__ __launch_bounds__(256) void k_pool(const float* __restrict__ h, const int* __restrict__ batch,
                                              int n, float* __restrict__ out) {
    int g = blockIdx.x;
    int lo = 0, hi = n;
    while (lo < hi) { int mid = (lo + hi) >> 1; if (batch[mid] < g) lo = mid + 1; else hi = mid; }
    int start = lo;
    hi = n;
    while (lo < hi) { int mid = (lo + hi) >> 1; if (batch[mid] < g + 1) lo = mid + 1; else hi = mid; }
    int end = lo;
    int lane = threadIdx.x & 63;
    int rs = threadIdx.x >> 6;
    float acc = 0.f;
    for (int r = start + rs; r < end; r += 4) acc += h[(size_t)r * HID + lane];
    __shared__ float sh[256];
    sh[threadIdx.x] = acc;
    __syncthreads();
    if (threadIdx.x < 64) {
        acc = sh[threadIdx.x] + sh[64 + threadIdx.x] + sh[128 + threadIdx.x] + sh[192 + threadIdx.x];
        out[(size_t)g * HID + threadIdx.x] = acc;
    }
}

// ============ driver ============

extern "C" void kernel_launch(void* const* d_in, const int* in_sizes, int n_in,
                              void* d_out, int out_size, void* d_ws, size_t ws_size,
                              hipStream_t stream) {
    const float* x     = (const float*)d_in[0];
    const int*   ei    = (const int*)d_in[1];
    const int*   batch = (const int*)d_in[2];
    const float* bnfg  = (const float*)d_in[3];
    const float* bnfb  = (const float*)d_in[4];
    const float* Wfeat = (const float*)d_in[5];
    const float* bfeat = (const float*)d_in[6];
    const float* bng   = (const float*)d_in[7];
    const float* bnb   = (const float*)d_in[8];
    const float* Ws    = (const float*)d_in[9];
    const float* bs    = (const float*)d_in[10];
    float* out = (float*)d_out;

    const int N   = in_sizes[2];
    const int E   = in_sizes[1] / 2;
    const int FIN = in_sizes[0] / N;
    const int L   = in_sizes[9] / (HID * HID);
    const int G   = out_size / HID;
    const int NB  = (N + 255) >> 8;
    const int SB  = 512;                 // stats stage-1 blocks

    char* w = (char*)d_ws;
    auto alloc = [&](size_t bytes) { char* p = w; w += (bytes + 255) & ~(size_t)255; return p; };
    int*   bcnt_d = (int*)alloc(256 * 4);
    int*   bcnt_s = (int*)alloc(256 * 4);
    size_t zero_bytes = (size_t)(w - (char*)d_ws);
    float* stats    = (float*)alloc(1024 * 4);
    float* spartial = (float*)alloc((size_t)SB * 256 * 4);   // 512 KB
    int*   bbase_d  = (int*)alloc(257 * 4);
    int*   cursor_d = (int*)alloc(256 * 4);
    int*   bbase_s  = (int*)alloc(257 * 4);
    int*   cursor_s = (int*)alloc(256 * 4);
    int*   rowptr   = (int*)alloc(((size_t)N + 1) * 4);
    int*   eidx     = (int*)alloc((size_t)E * 4);
    float* dis      = (float*)alloc((size_t)N * 4);
    float* Wf       = (float*)alloc((size_t)FIN * HID * 4);
    float* bf       = (float*)alloc(HID * 4);
    float* bufA     = (float*)alloc((size_t)N * HID * 4);
    ushort* bufB    = (ushort*)alloc((size_t)N * HID * 2);
    unsigned long long* bedge = (unsigned long long*)bufA;
    int* bsrc = (int*)bufB;

    hipMemsetAsync(d_ws, 0, zero_bytes, stream);

    int gG = (N + 63) / 64;

    // graph build
    k_bucket_hist<<<256, 256, 0, stream>>>(ei, E, NB, bcnt_d, bcnt_s);
    k_bucket_scan<<<1, 256, 0, stream>>>(bcnt_d, bcnt_s, NB, N, E,
                                         bbase_d, cursor_d, bbase_s, cursor_s, rowptr);
    k_scatter<<<256, 256, 0, stream>>>(ei, E, NB, cursor_d, cursor_s, bedge, bsrc);
    k_build_csr<<<NB, 256, 0, stream>>>(bedge, bbase_d, N, rowptr, eidx);
    k_outdeg<<<NB, 256, 0, stream>>>(bsrc, bbase_s, N, dis);

    // feature layer
    k_stats<128><<<SB, 256, 0, stream>>>(x, N, spartial);
    k_stats_final<128><<<256, 256, 0, stream>>>(spartial, SB, stats);
    k_fold<128><<<HID, 128, 0, stream>>>(stats, bnfg, bnfb, Wfeat, bfeat, 1.f / (float)N, Wf, bf, 1);
    k_gemm<128, true, false><<<gG, 256, 0, stream>>>(x, Wf, bf, dis, bufA, N);

    // GCN layers
    for (int l = 0; l < L; ++l) {
        k_stats<64><<<SB, 256, 0, stream>>>(bufA, N, spartial);
        k_stats_final<64><<<128, 256, 0, stream>>>(spartial, SB, stats);
        k_fold<64><<<HID, 64, 0, stream>>>(stats, bng + (size_t)l * HID, bnb + (size_t)l * HID,
                                           Ws + (size_t)l * HID * HID, bf /*unused*/,
                                           1.f / (float)N, Wf, bf, 0);
        k_gemm<64, false, true><<<gG, 256, 0, stream>>>(bufA, Wf, bf, dis, (void*)bufB, N);
        k_agg<<<(N + 7) / 8, 256, 0, stream>>>(bufB, rowptr, eidx, dis, bs + (size_t)l * HID, bufA, N);
    }

    k_pool<<<G, 256, 0, stream>>>(bufA, batch, N, out);
}

// Round 9
// 316.870 us; speedup vs baseline: 2.4729x; 1.0103x over previous
//
#include <hip/hip_runtime.h>
#include <math.h>

#define HID 64
#define BN_EPS 1e-5f
#define NBMAX 256

typedef unsigned int uint;
typedef unsigned short ushort;

// ============ radix-bucketed CSR build ============
// NOTE: edges packed to 32-bit ((dst&255)<<16 | src) — requires N < 65536 (N=50000 here).

__global__ __launch_bounds__(256) void k_bucket_hist(const int* __restrict__ ei, int E, int NB,
                                                     int* __restrict__ bcnt_d, int* __restrict__ bcnt_s) {
    __shared__ int hd[NBMAX], hs[NBMAX];
    int t = threadIdx.x;
    if (t < NB) { hd[t] = 0; hs[t] = 0; }
    __syncthreads();
    for (int e = blockIdx.x * 256 + t; e < E; e += gridDim.x * 256) {
        int src = ei[e], dst = ei[E + e];
        atomicAdd(&hs[src >> 8], 1);
        atomicAdd(&hd[dst >> 8], 1);
    }
    __syncthreads();
    if (t < NB) {
        if (hd[t]) atomicAdd(&bcnt_d[t], hd[t]);
        if (hs[t]) atomicAdd(&bcnt_s[t], hs[t]);
    }
}

__global__ __launch_bounds__(256) void k_bucket_scan(const int* __restrict__ bcnt_d, const int* __restrict__ bcnt_s,
                                                     int NB, int N, int E,
                                                     int* __restrict__ bbase_d, int* __restrict__ cursor_d,
                                                     int* __restrict__ bbase_s, int* __restrict__ cursor_s,
                                                     int* __restrict__ rowptr) {
    __shared__ int sh[256];
    int t = threadIdx.x;
    int v = (t < NB) ? bcnt_d[t] : 0;
    sh[t] = v; __syncthreads();
    for (int s = 1; s < 256; s <<= 1) { int u = (t >= s) ? sh[t - s] : 0; __syncthreads(); sh[t] += u; __syncthreads(); }
    int excl = sh[t] - v;
    if (t <= NB) bbase_d[t] = excl;
    if (t < NB) cursor_d[t] = excl;
    if (t == 0) rowptr[N] = E;
    __syncthreads();
    v = (t < NB) ? bcnt_s[t] : 0;
    sh[t] = v; __syncthreads();
    for (int s = 1; s < 256; s <<= 1) { int u = (t >= s) ? sh[t - s] : 0; __syncthreads(); sh[t] += u; __syncthreads(); }
    excl = sh[t] - v;
    if (t <= NB) bbase_s[t] = excl;
    if (t < NB) cursor_s[t] = excl;
}

__global__ __launch_bounds__(256) void k_scatter(const int* __restrict__ ei, int E, int NB,
                                                 int* __restrict__ cursor_d, int* __restrict__ cursor_s,
                                                 uint* __restrict__ bedge, int* __restrict__ bsrc) {
    __shared__ int hd[NBMAX], hs[NBMAX], curd[NBMAX], curs[NBMAX];
    int t = threadIdx.x;
    int chunk = (E + gridDim.x - 1) / gridDim.x;
    int e0 = blockIdx.x * chunk;
    int e1 = min(e0 + chunk, E);
    if (t < NB) { hd[t] = 0; hs[t] = 0; }
    __syncthreads();
    for (int e = e0 + t; e < e1; e += 256) {
        int src = ei[e], dst = ei[E + e];
        atomicAdd(&hd[dst >> 8], 1);
        atomicAdd(&hs[src >> 8], 1);
    }
    __syncthreads();
    if (t < NB) {
        curd[t] = hd[t] ? atomicAdd(&cursor_d[t], hd[t]) : 0;
        curs[t] = hs[t] ? atomicAdd(&cursor_s[t], hs[t]) : 0;
    }
    __syncthreads();
    for (int e = e0 + t; e < e1; e += 256) {
        int src = ei[e], dst = ei[E + e];
        int pd = atomicAdd(&curd[dst >> 8], 1);
        bedge[pd] = ((uint)(dst & 255) << 16) | (uint)src;   // N < 65536
        int ps = atomicAdd(&curs[src >> 8], 1);
        bsrc[ps] = src;
    }
}

__global__ __launch_bounds__(256) void k_build_csr(const uint* __restrict__ bedge,
                                                   const int* __restrict__ bbase_d, int N,
                                                   int* __restrict__ rowptr, int* __restrict__ eidx) {
    __shared__ int h[256], off[256], cur[256];
    int t = threadIdx.x, b = blockIdx.x;
    int base = bbase_d[b], end = bbase_d[b + 1];
    h[t] = 0; __syncthreads();
    for (int p = base + t; p < end; p += 256)
        atomicAdd(&h[(int)(bedge[p] >> 16) & 255], 1);
    __syncthreads();
    off[t] = h[t]; __syncthreads();
    for (int s = 1; s < 256; s <<= 1) { int u = (t >= s) ? off[t - s] : 0; __syncthreads(); off[t] += u; __syncthreads(); }
    int excl = off[t] - h[t];
    int node = (b << 8) + t;
    if (node <= N) rowptr[node] = base + excl;
    cur[t] = excl; __syncthreads();
    for (int p = base + t; p < end; p += 256) {
        uint be = bedge[p];
        int bin = (int)(be >> 16) & 255;
        int pos = atomicAdd(&cur[bin], 1);
        eidx[base + pos] = (int)(be & 0xffffu);
    }
}

__global__ __launch_bounds__(256) void k_outdeg(const int* __restrict__ bsrc, const int* __restrict__ bbase_s,
                                                int N, float* __restrict__ dis) {
    __shared__ int h[256];
    int t = threadIdx.x, b = blockIdx.x;
    int base = bbase_s[b], end = bbase_s[b + 1];
    h[t] = 0; __syncthreads();
    for (int p = base + t; p < end; p += 256) atomicAdd(&h[bsrc[p] & 255], 1);
    __syncthreads();
    int node = (b << 8) + t;
    if (node < N) dis[node] = rsqrtf((float)(h[t] + 1));
}

// ============ BN stats (only for input x; later layers fused into producers) ============

template <int F>
__global__ __launch_bounds__(256) void k_stats(const float* __restrict__ X, int n,
                                               float* __restrict__ partial) {
    constexpr int C4 = F / 4;
    constexpr int RPB = 256 / C4;
    int t = threadIdx.x;
    int c4 = t % C4;
    int rsub = t / C4;
    float4 s = make_float4(0.f, 0.f, 0.f, 0.f);
    float4 q = make_float4(0.f, 0.f, 0.f, 0.f);
    for (int r = blockIdx.x * RPB + rsub; r < n; r += gridDim.x * RPB) {
        float4 v = *(const float4*)(X + (size_t)r * F + 4 * c4);
        s.x += v.x; s.y += v.y; s.z += v.z; s.w += v.w;
        q.x = fmaf(v.x, v.x, q.x); q.y = fmaf(v.y, v.y, q.y);
        q.z = fmaf(v.z, v.z, q.z); q.w = fmaf(v.w, v.w, q.w);
    }
    __shared__ float4 shs[256], shq[256];
    shs[t] = s; shq[t] = q;
    __syncthreads();
    if (rsub == 0) {
        #pragma unroll
        for (int k = 1; k < RPB; k++) {
            float4 a = shs[t + k * C4], b = shq[t + k * C4];
            s.x += a.x; s.y += a.y; s.z += a.z; s.w += a.w;
            q.x += b.x; q.y += b.y; q.z += b.z; q.w += b.w;
        }
        float* p = partial + (size_t)blockIdx.x * (2 * F);
        *(float4*)(p + 4 * c4) = s;
        *(float4*)(p + F + 4 * c4) = q;
    }
}

// grid = 2F blocks, 256 threads: block j reduces partial[:, j] over nblocks entries.
template <int F>
__global__ __launch_bounds__(256) void k_stats_final(const float* __restrict__ partial, int nblocks,
                                                     float* __restrict__ stats) {
    int j = blockIdx.x;
    int t = threadIdx.x;
    float acc = 0.f;
    for (int b = t; b < nblocks; b += 256) acc += partial[(size_t)b * (2 * F) + j];
    __shared__ float sh[256];
    sh[t] = acc;
    __syncthreads();
    #pragma unroll
    for (int off = 128; off > 0; off >>= 1) {
        if (t < off) sh[t] += sh[t + off];
        __syncthreads();
    }
    if (t == 0) stats[j] = sh[0];
}

// ============ fold BN into linear ============

template <int K>
__global__ void k_fold(const float* __restrict__ stats, const float* __restrict__ gamma,
                       const float* __restrict__ beta, const float* __restrict__ W,
                       const float* __restrict__ bias, float n_inv,
                       float* __restrict__ Wout, float* __restrict__ bout, int has_bias) {
    int o = blockIdx.x;
    int f = threadIdx.x;
    float mu = stats[f] * n_inv;
    float var = stats[K + f] * n_inv - mu * mu;
    float a = gamma[f] * rsqrtf(var + BN_EPS);
    float w = W[(size_t)f * HID + o];
    Wout[(size_t)f * HID + o] = a * w;
    float contrib = (beta[f] - mu * a) * w;
    __shared__ float sh[K];
    sh[f] = contrib;
    __syncthreads();
    #pragma unroll
    for (int off = K / 2; off > 0; off >>= 1) {
        if (f < off) sh[f] += sh[f + off];
        __syncthreads();
    }
    if (f == 0) bout[o] = sh[0] + (has_bias ? bias[o] : 0.f);
}

// ============ GEMM: classic 2D tile; optional fused BN-stats epilogue ============

__device__ inline uint bf16pk(float a, float b) {
    uint ua = __builtin_bit_cast(uint, a);
    ua += 0x7fff + ((ua >> 16) & 1);
    uint ub = __builtin_bit_cast(uint, b);
    ub += 0x7fff + ((ub >> 16) & 1);
    return (ua >> 16) | (ub & 0xffff0000u);
}

template <int K, bool RELU, bool DIS, bool STATS>
__global__ __launch_bounds__(256) void k_gemm(const float* __restrict__ X, const float* __restrict__ W,
                                              const float* __restrict__ bias, const float* __restrict__ dis,
                                              void* __restrict__ out, int n,
                                              float* __restrict__ spartial) {
    constexpr int MT = 64;
    constexpr int KC = 64;
    constexpr int XS = 68;
    __shared__ float Xs[KC * XS];
    __shared__ float Ws[KC * HID];

    int t = threadIdx.x;
    int tx = t & 15;
    int ty = t >> 4;
    int row0 = blockIdx.x * MT;

    float acc[4][4];
    #pragma unroll
    for (int i = 0; i < 4; i++)
        #pragma unroll
        for (int j = 0; j < 4; j++) acc[i][j] = 0.f;

    for (int kc = 0; kc < K; kc += KC) {
        #pragma unroll
        for (int it = 0; it < 4; ++it) {
            int id = t + 256 * it;
            int r = id >> 4;
            int c4 = id & 15;
            float4 v = make_float4(0.f, 0.f, 0.f, 0.f);
            if (row0 + r < n) v = *(const float4*)(X + (size_t)(row0 + r) * K + kc + 4 * c4);
            int kk = 4 * c4;
            Xs[(kk + 0) * XS + r] = v.x;
            Xs[(kk + 1) * XS + r] = v.y;
            Xs[(kk + 2) * XS + r] = v.z;
            Xs[(kk + 3) * XS + r] = v.w;
        }
        {
            const float4* wsrc = (const float4*)(W + (size_t)kc * HID);
            #pragma unroll
            for (int it = 0; it < 4; ++it) {
                int id = t + 256 * it;
                ((float4*)Ws)[id] = wsrc[id];
            }
        }
        __syncthreads();

        #pragma unroll 8
        for (int k = 0; k < KC; ++k) {
            float4 xv = *(const float4*)&Xs[k * XS + 4 * ty];
            float4 wv = *(const float4*)&Ws[k * HID + 4 * tx];
            acc[0][0] = fmaf(xv.x, wv.x, acc[0][0]);
            acc[0][1] = fmaf(xv.x, wv.y, acc[0][1]);
            acc[0][2] = fmaf(xv.x, wv.z, acc[0][2]);
            acc[0][3] = fmaf(xv.x, wv.w, acc[0][3]);
            acc[1][0] = fmaf(xv.y, wv.x, acc[1][0]);
            acc[1][1] = fmaf(xv.y, wv.y, acc[1][1]);
            acc[1][2] = fmaf(xv.y, wv.z, acc[1][2]);
            acc[1][3] = fmaf(xv.y, wv.w, acc[1][3]);
            acc[2][0] = fmaf(xv.z, wv.x, acc[2][0]);
            acc[2][1] = fmaf(xv.z, wv.y, acc[2][1]);
            acc[2][2] = fmaf(xv.z, wv.z, acc[2][2]);
            acc[2][3] = fmaf(xv.z, wv.w, acc[2][3]);
            acc[3][0] = fmaf(xv.w, wv.x, acc[3][0]);
            acc[3][1] = fmaf(xv.w, wv.y, acc[3][1]);
            acc[3][2] = fmaf(xv.w, wv.z, acc[3][2]);
            acc[3][3] = fmaf(xv.w, wv.w, acc[3][3]);
        }
        __syncthreads();
    }

    float4 bv = *(const float4*)(bias + 4 * tx);
    float4 cs = make_float4(0.f, 0.f, 0.f, 0.f);   // per-thread col sums (STATS)
    float4 cq = make_float4(0.f, 0.f, 0.f, 0.f);
    #pragma unroll
    for (int i = 0; i < 4; ++i) {
        int row = row0 + 4 * ty + i;
        bool valid = row < n;
        float vx = acc[i][0] + bv.x, vy = acc[i][1] + bv.y;
        float vz = acc[i][2] + bv.z, vw = acc[i][3] + bv.w;
        if constexpr (DIS) {
            if (valid) {
                float d = dis[row];
                uint2 pk;
                pk.x = bf16pk(vx * d, vy * d);
                pk.y = bf16pk(vz * d, vw * d);
                *(uint2*)((ushort*)out + (size_t)row * HID + 4 * tx) = pk;
            }
        } else {
            float4 v;
            v.x = RELU ? fmaxf(vx, 0.f) : vx;
            v.y = RELU ? fmaxf(vy, 0.f) : vy;
            v.z = RELU ? fmaxf(vz, 0.f) : vz;
            v.w = RELU ? fmaxf(vw, 0.f) : vw;
            if (valid) *(float4*)((float*)out + (size_t)row * HID + 4 * tx) = v;
            if constexpr (STATS) {
                if (valid) {
                    cs.x += v.x; cs.y += v.y; cs.z += v.z; cs.w += v.w;
                    cq.x = fmaf(v.x, v.x, cq.x); cq.y = fmaf(v.y, v.y, cq.y);
                    cq.z = fmaf(v.z, v.z, cq.z); cq.w = fmaf(v.w, v.w, cq.w);
                }
            }
        }
    }
    if constexpr (STATS) {
        // reuse Xs as [16][64]x2 reduction buffer (k-loop done; last op was barrier)
        float* reds = Xs;
        float* redq = Xs + 1024;
        *(float4*)&reds[ty * 64 + 4 * tx] = cs;
        *(float4*)&redq[ty * 64 + 4 * tx] = cq;
        __syncthreads();
        if (t < 64) {
            float s = 0.f, q = 0.f;
            #pragma unroll
            for (int k = 0; k < 16; ++k) { s += reds[k * 64 + t]; q += redq[k * 64 + t]; }
            spartial[(size_t)blockIdx.x * 128 + t] = s;
            spartial[(size_t)blockIdx.x * 128 + 64 + t] = q;
        }
    }
}

// ============ aggregation (+ fused BN-stats partials for next layer) ============

__device__ inline float bfl(uint v) { return __builtin_bit_cast(float, v << 16); }
__device__ inline float bfh(uint v) { return __builtin_bit_cast(float, v & 0xffff0000u); }

template <bool STATS>
__global__ __launch_bounds__(256) void k_agg(const ushort* __restrict__ s, const int* __restrict__ rowptr,
                                             const int* __restrict__ eidx, const float* __restrict__ dis,
                                             const float* __restrict__ bias, float* __restrict__ out, int n,
                                             float* __restrict__ spartial) {
    int t = threadIdx.x;
    int nl = t >> 5;                 // node-local 0..7
    int li = t & 31;
    int i = blockIdx.x * 8 + nl;
    int f = li * 2;
    float2 r = make_float2(0.f, 0.f);
    bool valid = i < n;
    if (valid) {
        const uint* sp = (const uint*)s;
        uint v = sp[(size_t)i * 32 + li];
        float ax = bfl(v), ay = bfh(v);
        int q = rowptr[i], qe = rowptr[i + 1];
        for (; q + 8 <= qe; q += 8) {
            int j0 = eidx[q], j1 = eidx[q + 1], j2 = eidx[q + 2], j3 = eidx[q + 3];
            int j4 = eidx[q + 4], j5 = eidx[q + 5], j6 = eidx[q + 6], j7 = eidx[q + 7];
            uint v0 = sp[(size_t)j0 * 32 + li];
            uint v1 = sp[(size_t)j1 * 32 + li];
            uint v2 = sp[(size_t)j2 * 32 + li];
            uint v3 = sp[(size_t)j3 * 32 + li];
            uint v4 = sp[(size_t)j4 * 32 + li];
            uint v5 = sp[(size_t)j5 * 32 + li];
            uint v6 = sp[(size_t)j6 * 32 + li];
            uint v7 = sp[(size_t)j7 * 32 + li];
            ax += ((bfl(v0) + bfl(v1)) + (bfl(v2) + bfl(v3))) + ((bfl(v4) + bfl(v5)) + (bfl(v6) + bfl(v7)));
            ay += ((bfh(v0) + bfh(v1)) + (bfh(v2) + bfh(v3))) + ((bfh(v4) + bfh(v5)) + (bfh(v6) + bfh(v7)));
        }
        for (; q + 4 <= qe; q += 4) {
            int j0 = eidx[q], j1 = eidx[q + 1], j2 = eidx[q + 2], j3 = eidx[q + 3];
            uint v0 = sp[(size_t)j0 * 32 + li];
            uint v1 = sp[(size_t)j1 * 32 + li];
            uint v2 = sp[(size_t)j2 * 32 + li];
            uint v3 = sp[(size_t)j3 * 32 + li];
            ax += (bfl(v0) + bfl(v1)) + (bfl(v2) + bfl(v3));
            ay += (bfh(v0) + bfh(v1)) + (bfh(v2) + bfh(v3));
        }
        for (; q < qe; ++q) {
            uint vv = sp[(size_t)eidx[q] * 32 + li];
            ax += bfl(vv); ay += bfh(vv);
        }
        float dd = dis[i];
        float2 bb = *(const float2*)(bias + f);
        r.x = fmaxf(fmaf(dd, ax, bb.x), 0.f);
        r.y = fmaxf(fmaf(dd, ay, bb.y), 0.f);
        *(float2*)(out + (size_t)i * HID + f) = r;
    }
    if constexpr (STATS) {
        __shared__ float sh[8 * 64];
        sh[nl * 64 + f] = r.x;
        sh[nl * 64 + f + 1] = r.y;
        __syncthreads();
        if (t < 64) {
            float ss = 0.f, qq = 0.f;
            #pragma unroll
            for (int k = 0; k < 8; ++k) { float v = sh[k * 64 + t]; ss += v; qq = fmaf(v, v, qq); }
            spartial[(size_t)blockIdx.x * 128 + t] = ss;
            spartial[(size_t)blockIdx.x * 128 + 64 + t] = qq;
        }
    }
}

// ============ global_add_pool ============

__global__ __launch_bounds__(256) void k_pool(const float* __restrict__ h, const int* __restrict__ batch,
                                              int n, float* __restrict__ out) {
    int g = blockIdx.x;
    int lo = 0, hi = n;
    while (lo < hi) { int mid = (lo + hi) >> 1; if (batch[mid] < g) lo = mid + 1; else hi = mid; }
    int start = lo;
    hi = n;
    while (lo < hi) { int mid = (lo + hi) >> 1; if (batch[mid] < g + 1) lo = mid + 1; else hi = mid; }
    int end = lo;
    int lane = threadIdx.x & 63;
    int rs = threadIdx.x >> 6;
    float acc = 0.f;
    for (int r = start + rs; r < end; r += 4) acc += h[(size_t)r * HID + lane];
    __shared__ float sh[256];
    sh[threadIdx.x] = acc;
    __syncthreads();
    if (threadIdx.x < 64) {
        acc = sh[threadIdx.x] + sh[64 + threadIdx.x] + sh[128 + threadIdx.x] + sh[192 + threadIdx.x];
        out[(size_t)g * HID + threadIdx.x] = acc;
    }
}

// ============ driver ============

extern "C" void kernel_launch(void* const* d_in, const int* in_sizes, int n_in,
                              void* d_out, int out_size, void* d_ws, size_t ws_size,
                              hipStream_t stream) {
    const float* x     = (const float*)d_in[0];
    const int*   ei    = (const int*)d_in[1];
    const int*   batch = (const int*)d_in[2];
    const float* bnfg  = (const float*)d_in[3];
    const float* bnfb  = (const float*)d_in[4];
    const float* Wfeat = (const float*)d_in[5];
    const float* bfeat = (const float*)d_in[6];
    const float* bng   = (const float*)d_in[7];
    const float* bnb   = (const float*)d_in[8];
    const float* Ws    = (const float*)d_in[9];
    const float* bs    = (const float*)d_in[10];
    float* out = (float*)d_out;

    const int N   = in_sizes[2];
    const int E   = in_sizes[1] / 2;
    const int FIN = in_sizes[0] / N;
    const int L   = in_sizes[9] / (HID * HID);
    const int G   = out_size / HID;
    const int NB  = (N + 255) >> 8;
    const int SB  = 512;                    // stats<128> stage-1 blocks
    const int gG  = (N + 63) / 64;          // gemm blocks
    const int gA  = (N + 7) / 8;            // agg blocks

    char* w = (char*)d_ws;
    auto alloc = [&](size_t bytes) { char* p = w; w += (bytes + 255) & ~(size_t)255; return p; };
    int*   bcnt_d = (int*)alloc(256 * 4);
    int*   bcnt_s = (int*)alloc(256 * 4);
    size_t zero_bytes = (size_t)(w - (char*)d_ws);
    float* stats    = (float*)alloc(1024 * 4);
    size_t spmax    = (size_t)(SB > gA ? SB : gA) * 256 * 4;
    float* spartial = (float*)alloc(spmax);
    int*   bbase_d  = (int*)alloc(257 * 4);
    int*   cursor_d = (int*)alloc(256 * 4);
    int*   bbase_s  = (int*)alloc(257 * 4);
    int*   cursor_s = (int*)alloc(256 * 4);
    int*   rowptr   = (int*)alloc(((size_t)N + 1) * 4);
    int*   eidx     = (int*)alloc((size_t)E * 4);
    float* dis      = (float*)alloc((size_t)N * 4);
    float* Wf       = (float*)alloc((size_t)FIN * HID * 4);
    float* bf       = (float*)alloc(HID * 4);
    float* bufA     = (float*)alloc((size_t)N * HID * 4);
    ushort* bufB    = (ushort*)alloc((size_t)N * HID * 2);
    uint* bedge = (uint*)bufA;     // E*4 <= N*HID*4
    int*  bsrc  = (int*)bufB;      // E*4 <= N*HID*2

    hipMemsetAsync(d_ws, 0, zero_bytes, stream);

    // graph build
    k_bucket_hist<<<256, 256, 0, stream>>>(ei, E, NB, bcnt_d, bcnt_s);
    k_bucket_scan<<<1, 256, 0, stream>>>(bcnt_d, bcnt_s, NB, N, E,
                                         bbase_d, cursor_d, bbase_s, cursor_s, rowptr);
    k_scatter<<<256, 256, 0, stream>>>(ei, E, NB, cursor_d, cursor_s, bedge, bsrc);
    k_build_csr<<<NB, 256, 0, stream>>>(bedge, bbase_d, N, rowptr, eidx);
    k_outdeg<<<NB, 256, 0, stream>>>(bsrc, bbase_s, N, dis);

    // feature layer: stats(x) -> fold -> gemm (fused stats of output)
    k_stats<128><<<SB, 256, 0, stream>>>(x, N, spartial);
    k_stats_final<128><<<256, 256, 0, stream>>>(spartial, SB, stats);
    k_fold<128><<<HID, 128, 0, stream>>>(stats, bnfg, bnfb, Wfeat, bfeat, 1.f / (float)N, Wf, bf, 1);
    k_gemm<128, true, false, true><<<gG, 256, 0, stream>>>(x, Wf, bf, dis, bufA, N, spartial);
    int spblocks = gG;

    // GCN layers
    for (int l = 0; l < L; ++l) {
        k_stats_final<64><<<128, 256, 0, stream>>>(spartial, spblocks, stats);
        k_fold<64><<<HID, 64, 0, stream>>>(stats, bng + (size_t)l * HID, bnb + (size_t)l * HID,
                                           Ws + (size_t)l * HID * HID, bf /*unused*/,
                                           1.f / (float)N, Wf, bf, 0);
        k_gemm<64, false, true, false><<<gG, 256, 0, stream>>>(bufA, Wf, bf, dis, (void*)bufB, N, nullptr);
        if (l < L - 1) {
            k_agg<true><<<gA, 256, 0, stream>>>(bufB, rowptr, eidx, dis, bs + (size_t)l * HID, bufA, N, spartial);
            spblocks = gA;
        } else {
            k_agg<false><<<gA, 256, 0, stream>>>(bufB, rowptr, eidx, dis, bs + (size_t)l * HID, bufA, N, nullptr);
        }
    }

    k_pool<<<G, 256, 0, stream>>>(bufA, batch, N, out);
}